// Round 5
// baseline (1769.326 us; speedup 1.0000x reference)
//
#include <hip/hip_runtime.h>
#include <hip/hip_bf16.h>
#include <string.h>

#define N_NODES 100000
#define N_EDGES 20000
#define NNZ     1600000

// CSR-build params: fixed-capacity buckets (mean+>10 sigma), no global scan
#define CHUNK   8192
#define NBE     157            // edge buckets (128 keys each), kshift=17
#define NBN     391            // node buckets (256 keys each), kshift=15
#define CAP_E   11264          // mean 10191, sigma ~101
#define CAP_N   4864           // mean 4092,  sigma ~64
#define NBLK_BIN ((NNZ + CHUNK - 1) / CHUNK)   // 196

// ------------------------------------------------------------ bf16 helpers

__device__ __forceinline__ unsigned short f2bf(float f) {
    unsigned int u = __float_as_uint(f);
    unsigned int r = (u + 0x7fffu + ((u >> 16) & 1u)) >> 16;   // RNE
    return (unsigned short)r;
}
__device__ __forceinline__ float bflo(unsigned int v) { return __uint_as_float(v << 16); }
__device__ __forceinline__ float bfhi(unsigned int v) { return __uint_as_float(v & 0xffff0000u); }
__device__ __forceinline__ unsigned int packbf(float lo, float hi) {
    return ((unsigned int)f2bf(hi) << 16) | (unsigned int)f2bf(lo);
}

__device__ __forceinline__ void async_copy16(const void* g, void* l) {
    __builtin_amdgcn_global_load_lds((const __attribute__((address_space(1))) void*)g,
                                     (__attribute__((address_space(3))) void*)l, 16, 0, 0);
}

typedef __attribute__((ext_vector_type(8))) short bf16x8;
typedef __attribute__((ext_vector_type(4))) float f32x4;

// NT load for the csr index streams in sliced kernels: read 8x (once per
// slice), no reuse -> evict-first keeps the gather table resident in L2
__device__ __forceinline__ int ntload_i(const int* p) {
    return __builtin_nontemporal_load(p);
}

// ---------------------------------------------------- CSR build (capacity buckets)

// one pass over both index arrays: LDS-histogram, reserve global runs,
// scatter packed (key|val) into bucket-strided staging for BOTH directions
__global__ __launch_bounds__(256)
void bin_both(const int* __restrict__ node_idx, const int* __restrict__ edge_idx,
              int* __restrict__ curE, int* __restrict__ curN,
              unsigned int* __restrict__ stagedE, unsigned int* __restrict__ stagedN) {
    __shared__ int hE[NBE], gE[NBE], hN[NBN], gN[NBN];
    int t = threadIdx.x;
    for (int i = t; i < NBE; i += 256) hE[i] = 0;
    for (int i = t; i < NBN; i += 256) hN[i] = 0;
    __syncthreads();
    long base = (long)blockIdx.x * CHUNK;
    for (int k = 0; k < CHUNK / 256; k++) {
        long i = base + t + k * 256;
        if (i < NNZ) {
            atomicAdd(&hE[edge_idx[i] >> 7], 1);
            atomicAdd(&hN[node_idx[i] >> 8], 1);
        }
    }
    __syncthreads();
    for (int i = t; i < NBE; i += 256) gE[i] = hE[i] ? atomicAdd(&curE[i], hE[i]) : 0;
    for (int i = t; i < NBN; i += 256) gN[i] = hN[i] ? atomicAdd(&curN[i], hN[i]) : 0;
    __syncthreads();
    for (int i = t; i < NBE; i += 256) hE[i] = 0;
    for (int i = t; i < NBN; i += 256) hN[i] = 0;
    __syncthreads();
    for (int k = 0; k < CHUNK / 256; k++) {
        long i = base + t + k * 256;
        if (i < NNZ) {
            int e = edge_idx[i], n = node_idx[i];
            int be = e >> 7, bn = n >> 8;
            int pe = gE[be] + atomicAdd(&hE[be], 1);
            if (pe < CAP_E) stagedE[(size_t)be * CAP_E + pe] = ((unsigned)e << 17) | (unsigned)n;
            int pn = gN[bn] + atomicAdd(&hN[bn], 1);
            if (pn < CAP_N) stagedN[(size_t)bn * CAP_N + pn] = ((unsigned)n << 15) | (unsigned)e;
        }
    }
}

// per bucket: per-key count -> local scan -> off/end/inv -> scatter to csr
__global__ __launch_bounds__(256)
void build_csr2(const unsigned int* __restrict__ staged, const int* __restrict__ cnts,
                int cap, int kshift, int bshift, int nkey,
                int* __restrict__ off, int* __restrict__ endv,
                float* __restrict__ inv, int* __restrict__ csr) {
    __shared__ int cnt[256];
    __shared__ int cur[256];
    int b = blockIdx.x, t = threadIdx.x;
    int kpb = 1 << bshift;
    int key0 = b << bshift;
    unsigned int vmask = (1u << kshift) - 1u;
    int s = b * cap;
    int n = min(cnts[b], cap);
    if (t < kpb) cnt[t] = 0;
    __syncthreads();
    for (int j = t; j < n; j += 256)
        atomicAdd(&cnt[(int)(staged[s + j] >> kshift) - key0], 1);
    __syncthreads();
    int v = (t < kpb) ? cnt[t] : 0;
    cur[t] = v; __syncthreads();
    for (int st = 1; st < 256; st <<= 1) {
        int x = (t >= st) ? cur[t - st] : 0;
        __syncthreads();
        cur[t] += x;
        __syncthreads();
    }
    int excl = cur[t] - v;
    __syncthreads();
    if (t < kpb) {
        int key = key0 + t;
        if (key < nkey) {
            off[key] = s + excl;
            endv[key] = s + excl + v;
            inv[key] = (v > 0) ? 1.0f / (float)v : 0.0f;
        }
        cur[t] = excl;
    }
    __syncthreads();
    for (int j = t; j < n; j += 256) {
        unsigned int pk = staged[s + j];
        int k = (int)(pk >> kshift) - key0;
        int pos = s + atomicAdd(&cur[k], 1);
        csr[pos] = (int)(pk & vmask);
    }
}

// ------------------------------------------------------------ prep kernels

// vectorized: 40 threads/row x 8 cols, float4 x2 in, packed-bf16 uint4 out
__global__ __launch_bounds__(256)
void convert_pad_x_v(const float* __restrict__ x, unsigned short* __restrict__ xb) {
    int t = threadIdx.x;
    if (t >= 240) return;
    int c = t % 40;
    int r = blockIdx.x * 6 + t / 40;
    if (r >= N_NODES) return;
    const float* xr = x + (size_t)r * 300 + c * 8;
    uint4 ov;
    if (c < 37) {
        float4 a = ((const float4*)xr)[0];
        float4 b = ((const float4*)xr)[1];
        ov.x = packbf(a.x, a.y); ov.y = packbf(a.z, a.w);
        ov.z = packbf(b.x, b.y); ov.w = packbf(b.z, b.w);
    } else if (c == 37) {                    // cols 296-299 valid, 300-303 pad
        float4 a = ((const float4*)xr)[0];
        ov.x = packbf(a.x, a.y); ov.y = packbf(a.z, a.w);
        ov.z = 0u; ov.w = 0u;
    } else {                                 // cols 304-319 pad
        ov.x = ov.y = ov.z = ov.w = 0u;
    }
    *(uint4*)(xb + (size_t)r * 320 + c * 8) = ov;
}

// all three weight transposes in one launch (grid 640)
__global__ void transpose_all(const float* __restrict__ W1, const float* __restrict__ W2,
                              const float* __restrict__ W3,
                              unsigned short* __restrict__ Wt1, unsigned short* __restrict__ Wt2,
                              unsigned short* __restrict__ Wt3) {
    int b = blockIdx.x;
    int t = threadIdx.x;
    if (b < 256) {
        for (int k = t; k < 320; k += 256)
            Wt1[(size_t)b * 320 + k] = (k < 300) ? f2bf(W1[(size_t)k * 256 + b]) : (unsigned short)0;
    } else if (b < 512) {
        int n = b - 256;
        Wt2[(size_t)n * 256 + t] = f2bf(W2[(size_t)t * 256 + n]);
    } else {
        int n = b - 512;
        Wt3[(size_t)n * 256 + t] = f2bf(W3[(size_t)t * 128 + n]);
    }
}

// ------------------------------------------------------------ bf16 MFMA GEMM

__global__ __launch_bounds__(256)
void gemm_bf16(const unsigned short* __restrict__ A,
               const unsigned short* __restrict__ Bt,
               unsigned short* __restrict__ C,
               int M, int Kp, int N) {
    __shared__ unsigned short As[128 * 32];
    __shared__ unsigned short Bs[128 * 32];
    int tid = threadIdx.x;
    int lane = tid & 63;
    int w = tid >> 6;
    int row0 = blockIdx.x * 128;
    int col0 = blockIdx.y * 128;
    int wm = w & 1, wn = w >> 1;

    f32x4 acc[4][4];
    #pragma unroll
    for (int i = 0; i < 4; i++)
        #pragma unroll
        for (int j = 0; j < 4; j++) acc[i][j] = (f32x4){0.f, 0.f, 0.f, 0.f};

    int sr = lane >> 2;
    int sc = lane & 3;

    for (int k0 = 0; k0 < Kp; k0 += 32) {
        #pragma unroll
        for (int c = 0; c < 2; c++) {
            int r = w * 32 + c * 16 + sr;
            int gr = row0 + r; if (gr >= M) gr = M - 1;
            const unsigned short* g = A + (size_t)gr * Kp + k0 + sc * 8;
            async_copy16(g, (void*)(As + (w * 32 + c * 16) * 32));
        }
        #pragma unroll
        for (int c = 0; c < 2; c++) {
            int r = w * 32 + c * 16 + sr;
            const unsigned short* g = Bt + (size_t)(col0 + r) * Kp + k0 + sc * 8;
            async_copy16(g, (void*)(Bs + (w * 32 + c * 16) * 32));
        }
        __syncthreads();

        bf16x8 a[4], b[4];
        #pragma unroll
        for (int i = 0; i < 4; i++)
            a[i] = *(const bf16x8*)(As + (wm * 64 + i * 16 + (lane & 15)) * 32 + (lane >> 4) * 8);
        #pragma unroll
        for (int j = 0; j < 4; j++)
            b[j] = *(const bf16x8*)(Bs + (wn * 64 + j * 16 + (lane & 15)) * 32 + (lane >> 4) * 8);
        #pragma unroll
        for (int i = 0; i < 4; i++)
            #pragma unroll
            for (int j = 0; j < 4; j++)
                acc[i][j] = __builtin_amdgcn_mfma_f32_16x16x32_bf16(a[i], b[j], acc[i][j], 0, 0, 0);
        __syncthreads();
    }

    int crow = (lane >> 4) * 4;
    int ccol = lane & 15;
    #pragma unroll
    for (int i = 0; i < 4; i++)
        #pragma unroll
        for (int r = 0; r < 4; r++) {
            int gr = row0 + wm * 64 + i * 16 + crow + r;
            if (gr < M) {
                #pragma unroll
                for (int j = 0; j < 4; j++) {
                    int gc = col0 + wn * 64 + j * 16 + ccol;
                    C[(size_t)gr * N + gc] = f2bf(acc[i][j][r]);
                }
            }
        }
}

// ------------------------------- XCD-sliced segment aggregation -------------
// Diagnosis chain (rounds 0-4): dur invariant under MLP changes; NT probe
// (-17% with FETCH unchanged) => wall = miss-path concurrency x latency.
// Fix: slice the feature dim across XCDs. Block b handles only the 64-B
// column-slice (b%8) of every row; consecutive blockIdx round-robin XCDs, so
// per-XCD L2 working set drops 51.2->6.4 MB (edge) / 10.2->1.3 MB (node):
// L2 misses become hits, avg latency ~3x down, same-MSHR throughput up.
// Wave layout: sub=lane&3 (16-B piece of the 64-B slice), rq=lane>>2 (16 rows
// in flight per load); reduce over rq via 4 shfl steps; lanes 0-3 write.
// csr index stream is read 8x (once per slice) -> NT loads, no L2 pollution.

#define ACC8(v)  { a[0] += bflo((v).x); a[1] += bfhi((v).x); \
                   a[2] += bflo((v).y); a[3] += bfhi((v).y); \
                   a[4] += bflo((v).z); a[5] += bfhi((v).z); \
                   a[6] += bflo((v).w); a[7] += bfhi((v).w); }

#define RED16()  _Pragma("unroll") \
                 for (int k = 0; k < 8; k++) { \
                     a[k] += __shfl_down(a[k], 32); \
                     a[k] += __shfl_down(a[k], 16); \
                     a[k] += __shfl_down(a[k], 8); \
                     a[k] += __shfl_down(a[k], 4); \
                 }

// 512-B rows, 8 slices; 4 segs per wave, 16 segs per block
__global__ __launch_bounds__(256)
void edge_agg_sl(const unsigned short* __restrict__ X, const int* __restrict__ off,
                 const int* __restrict__ endv, const int* __restrict__ csr,
                 const float* __restrict__ inv, unsigned short* __restrict__ E) {
    int wv = threadIdx.x >> 6, lane = threadIdx.x & 63;
    int slice = blockIdx.x & 7;
    int seg0 = (blockIdx.x >> 3) * 16 + wv * 4;
    int sub = lane & 3, rq = lane >> 2;
    unsigned lo = ((unsigned)slice << 6) + ((unsigned)sub << 4);
    const char* Xc = (const char*)X;
    #pragma unroll 1
    for (int ss = 0; ss < 4; ss++) {
        int seg = seg0 + ss;
        if (seg >= N_EDGES) break;
        int s = off[seg], t = endv[seg];
        float a[8] = {0.f, 0.f, 0.f, 0.f, 0.f, 0.f, 0.f, 0.f};
        int j = s;
        for (; j + 64 <= t; j += 64) {           // 4 x 16 rows in flight
            uint4 v[4];
            #pragma unroll
            for (int q = 0; q < 4; q++) {
                unsigned idx = (unsigned)ntload_i(&csr[j + q * 16 + rq]);
                v[q] = *(const uint4*)(Xc + ((idx << 9) + lo));
            }
            __builtin_amdgcn_sched_barrier(0);
            #pragma unroll
            for (int q = 0; q < 4; q++) ACC8(v[q]);
        }
        for (; j + 16 <= t; j += 16) {
            unsigned idx = (unsigned)ntload_i(&csr[j + rq]);
            uint4 v = *(const uint4*)(Xc + ((idx << 9) + lo));
            ACC8(v);
        }
        if (j + rq < t) {                        // predicated tail (<16 rows)
            unsigned idx = (unsigned)ntload_i(&csr[j + rq]);
            uint4 v = *(const uint4*)(Xc + ((idx << 9) + lo));
            ACC8(v);
        }
        RED16();
        if (lane < 4) {                          // sub == lane here
            float bi = inv[seg];
            uint4 o;
            o.x = packbf(a[0] * bi, a[1] * bi); o.y = packbf(a[2] * bi, a[3] * bi);
            o.z = packbf(a[4] * bi, a[5] * bi); o.w = packbf(a[6] * bi, a[7] * bi);
            *(uint4*)((char*)E + (size_t)seg * 512 + lo) = o;
        }
    }
}

// 512-B rows, 8 slices; bias + leaky-relu epilogue; 8 segs/wave, 32/block
__global__ __launch_bounds__(256)
void node_agg_sl(const unsigned short* __restrict__ Eb, const int* __restrict__ off,
                 const int* __restrict__ endv, const int* __restrict__ csr,
                 const float* __restrict__ inv, const float* __restrict__ bias,
                 unsigned short* __restrict__ outB) {
    int wv = threadIdx.x >> 6, lane = threadIdx.x & 63;
    int slice = blockIdx.x & 7;
    int seg0 = (blockIdx.x >> 3) * 32 + wv * 8;
    int sub = lane & 3, rq = lane >> 2;
    unsigned lo = ((unsigned)slice << 6) + ((unsigned)sub << 4);
    const char* Ec = (const char*)Eb;
    float4 b0 = ((const float4*)bias)[slice * 8 + sub * 2];
    float4 b1 = ((const float4*)bias)[slice * 8 + sub * 2 + 1];
    #pragma unroll 1
    for (int ss = 0; ss < 8; ss++) {
        int seg = seg0 + ss;
        if (seg >= N_NODES) break;
        int s = off[seg], t = endv[seg];
        float a[8] = {0.f, 0.f, 0.f, 0.f, 0.f, 0.f, 0.f, 0.f};
        int j = s;
        for (; j + 16 <= t; j += 16) {
            unsigned idx = (unsigned)ntload_i(&csr[j + rq]);
            uint4 v = *(const uint4*)(Ec + ((idx << 9) + lo));
            ACC8(v);
        }
        if (j + rq < t) {
            unsigned idx = (unsigned)ntload_i(&csr[j + rq]);
            uint4 v = *(const uint4*)(Ec + ((idx << 9) + lo));
            ACC8(v);
        }
        RED16();
        if (lane < 4) {
            float di = inv[seg];
            float o0 = a[0] * di + b0.x, o1 = a[1] * di + b0.y;
            float o2 = a[2] * di + b0.z, o3 = a[3] * di + b0.w;
            float o4 = a[4] * di + b1.x, o5 = a[5] * di + b1.y;
            float o6 = a[6] * di + b1.z, o7 = a[7] * di + b1.w;
            o0 = (o0 > 0.f) ? o0 : 0.01f * o0;  o1 = (o1 > 0.f) ? o1 : 0.01f * o1;
            o2 = (o2 > 0.f) ? o2 : 0.01f * o2;  o3 = (o3 > 0.f) ? o3 : 0.01f * o3;
            o4 = (o4 > 0.f) ? o4 : 0.01f * o4;  o5 = (o5 > 0.f) ? o5 : 0.01f * o5;
            o6 = (o6 > 0.f) ? o6 : 0.01f * o6;  o7 = (o7 > 0.f) ? o7 : 0.01f * o7;
            uint4 o;
            o.x = packbf(o0, o1); o.y = packbf(o2, o3);
            o.z = packbf(o4, o5); o.w = packbf(o6, o7);
            *(uint4*)((char*)outB + (size_t)seg * 512 + lo) = o;
        }
    }
}

// 256-B rows, 4 slices (each XCD pinned to slice xcd&3); fp32 out + bias
__global__ __launch_bounds__(256)
void node_agg128f_sl(const unsigned short* __restrict__ Eb, const int* __restrict__ off,
                     const int* __restrict__ endv, const int* __restrict__ csr,
                     const float* __restrict__ inv, const float* __restrict__ bias,
                     float* __restrict__ outF) {
    int wv = threadIdx.x >> 6, lane = threadIdx.x & 63;
    int slice = blockIdx.x & 3;
    int seg0 = (blockIdx.x >> 2) * 32 + wv * 8;
    int sub = lane & 3, rq = lane >> 2;
    unsigned lo = ((unsigned)slice << 6) + ((unsigned)sub << 4);
    const char* Ec = (const char*)Eb;
    float4 b0 = ((const float4*)bias)[slice * 8 + sub * 2];
    float4 b1 = ((const float4*)bias)[slice * 8 + sub * 2 + 1];
    #pragma unroll 1
    for (int ss = 0; ss < 8; ss++) {
        int seg = seg0 + ss;
        if (seg >= N_NODES) break;
        int s = off[seg], t = endv[seg];
        float a[8] = {0.f, 0.f, 0.f, 0.f, 0.f, 0.f, 0.f, 0.f};
        int j = s;
        for (; j + 16 <= t; j += 16) {
            unsigned idx = (unsigned)ntload_i(&csr[j + rq]);
            uint4 v = *(const uint4*)(Ec + ((idx << 8) + lo));
            ACC8(v);
        }
        if (j + rq < t) {
            unsigned idx = (unsigned)ntload_i(&csr[j + rq]);
            uint4 v = *(const uint4*)(Ec + ((idx << 8) + lo));
            ACC8(v);
        }
        RED16();
        if (lane < 4) {
            float di = inv[seg];
            float4 o0 = make_float4(a[0] * di + b0.x, a[1] * di + b0.y,
                                    a[2] * di + b0.z, a[3] * di + b0.w);
            float4 o1 = make_float4(a[4] * di + b1.x, a[5] * di + b1.y,
                                    a[6] * di + b1.z, a[7] * di + b1.w);
            ((float4*)outF)[(size_t)seg * 32 + slice * 8 + sub * 2]     = o0;
            ((float4*)outF)[(size_t)seg * 32 + slice * 8 + sub * 2 + 1] = o1;
        }
    }
}

// ------------------------------------------------------------- attention pool

__global__ __launch_bounds__(256)
void logits_kernel(const float* __restrict__ H, const float* __restrict__ aW,
                   const float* __restrict__ aB, float* __restrict__ logits,
                   float* __restrict__ pmax, int N) {
    int lane = threadIdx.x & 63;
    int wave = threadIdx.x >> 6;
    int waveGlobal = blockIdx.x * 4 + wave;
    int stride = gridDim.x * 4;
    float2 w2 = ((const float2*)aW)[lane];
    float lmax = -1e30f;
    float ab = aB[0];
    for (int n = waveGlobal; n < N; n += stride) {
        float2 h2 = ((const float2*)(H + (size_t)n * 128))[lane];
        float d = h2.x * w2.x + h2.y * w2.y;
        #pragma unroll
        for (int s = 32; s > 0; s >>= 1) d += __shfl_xor(d, s, 64);
        float lg = d + ab;
        if (lane == 0) logits[n] = lg;
        lmax = fmaxf(lmax, lg);
    }
    __shared__ float wmax[4];
    if (lane == 0) wmax[wave] = lmax;
    __syncthreads();
    if (threadIdx.x == 0) {
        float m = fmaxf(fmaxf(wmax[0], wmax[1]), fmaxf(wmax[2], wmax[3]));
        pmax[blockIdx.x] = m;
    }
}

// global-max reduction folded in (reads pmax[400] per block, ~1 us total)
__global__ __launch_bounds__(128)
void weighted_sum(const float* __restrict__ H, const float* __restrict__ logits,
                  const float* __restrict__ pmax, float* __restrict__ gacc,
                  float* __restrict__ gsum, int N) {
    int f = threadIdx.x;
    __shared__ float smax[2];
    float m = -1e30f;
    for (int i = f; i < 400; i += 128) m = fmaxf(m, pmax[i]);
    #pragma unroll
    for (int s = 32; s > 0; s >>= 1) m = fmaxf(m, __shfl_xor(m, s, 64));
    if ((f & 63) == 0) smax[f >> 6] = m;
    __syncthreads();
    float mx = fmaxf(smax[0], smax[1]);
    float acc = 0.f, ls = 0.f;
    for (int n = blockIdx.x; n < N; n += gridDim.x) {
        float w = __expf(logits[n] - mx);
        acc += w * H[(size_t)n * 128 + f];
        if (f == 0) ls += w;
    }
    atomicAdd(&gacc[f], acc);
    if (f == 0) atomicAdd(gsum, ls);
}

__global__ __launch_bounds__(128)
void finalize(const float* __restrict__ gacc, const float* __restrict__ gsum,
              float* __restrict__ out) {
    int f = threadIdx.x;
    out[f] = gacc[f] / gsum[0];
}

// ---------------------------------------------------------------- launch

extern "C" void kernel_launch(void* const* d_in, const int* in_sizes, int n_in,
                              void* d_out, int out_size, void* d_ws, size_t ws_size,
                              hipStream_t stream) {
    const float* x        = (const float*)d_in[0];
    const int*   node_idx = (const int*)d_in[1];
    const int*   edge_idx = node_idx + NNZ;
    const float* W1 = (const float*)d_in[2];
    const float* b1 = (const float*)d_in[3];
    const float* W2 = (const float*)d_in[4];
    const float* b2 = (const float*)d_in[5];
    const float* W3 = (const float*)d_in[6];
    const float* b3 = (const float*)d_in[7];
    const float* aW = (const float*)d_in[8];
    const float* aB = (const float*)d_in[9];
    float* out = (float*)d_out;

    char* ws = (char*)d_ws;
    size_t off = 0;
    auto take = [&](size_t bytes) -> char* {
        char* r = ws + off;
        off = (off + bytes + 255) & ~(size_t)255;
        return r;
    };

    char* cur_base = take((size_t)(NBE + NBN) * 4);   // zeroed cursors
    int* curE = (int*)cur_base;
    int* curN = curE + NBE;
    int*   offE = (int*)take((size_t)N_EDGES * 4);
    int*   endE = (int*)take((size_t)N_EDGES * 4);
    int*   offN = (int*)take((size_t)N_NODES * 4);
    int*   endN = (int*)take((size_t)N_NODES * 4);
    float* Binv = (float*)take((size_t)N_EDGES * 4);
    float* Dinv = (float*)take((size_t)N_NODES * 4);
    int*   csrE = (int*)take((size_t)NBE * CAP_E * 4);
    int*   csrN = (int*)take((size_t)NBN * CAP_N * 4);

    unsigned short* xb  = (unsigned short*)take((size_t)N_NODES * 320 * 2);  // reused as h3 fp32
    unsigned short* Wt1 = (unsigned short*)take((size_t)256 * 320 * 2);
    unsigned short* Wt2 = (unsigned short*)take((size_t)256 * 256 * 2);
    unsigned short* Wt3 = (unsigned short*)take((size_t)128 * 256 * 2);
    unsigned short* xw   = (unsigned short*)take((size_t)N_NODES * 256 * 2); // layer-1 gemm out
    unsigned short* hb   = (unsigned short*)take((size_t)N_NODES * 256 * 2); // node features
    unsigned short* eagg = (unsigned short*)take((size_t)N_EDGES * 256 * 2); // pre-GEMM edge sums (L2/3)
    unsigned short* eb   = (unsigned short*)take((size_t)N_EDGES * 256 * 2); // edge table
    float* h3 = (float*)xb;

    // staging aliases xw (dead until gemm1; build_csr2 consumes it first)
    unsigned int* stagedE = (unsigned int*)xw;
    unsigned int* stagedN = stagedE + (size_t)NBE * CAP_E;

    float* logits = (float*)take((size_t)N_NODES * 4);
    float* pmax   = (float*)take(400 * 4);
    char* acc_base = take((128 + 1) * 4);
    float* gacc = (float*)acc_base;
    float* gsum = gacc + 128;

    hipMemsetAsync(cur_base, 0, (size_t)(NBE + NBN) * 4, stream);
    hipMemsetAsync(acc_base, 0, (128 + 1) * 4, stream);

    // ---- CSR build: one binning sweep + per-bucket build (both directions)
    bin_both<<<NBLK_BIN, 256, 0, stream>>>(node_idx, edge_idx, curE, curN, stagedE, stagedN);
    build_csr2<<<NBE, 256, 0, stream>>>(stagedE, curE, CAP_E, 17, 7, N_EDGES, offE, endE, Binv, csrE);
    build_csr2<<<NBN, 256, 0, stream>>>(stagedN, curN, CAP_N, 15, 8, N_NODES, offN, endN, Dinv, csrN);

    // ---- prep
    convert_pad_x_v<<<(N_NODES + 5) / 6, 256, 0, stream>>>(x, xb);
    transpose_all<<<640, 256, 0, stream>>>(W1, W2, W3, Wt1, Wt2, Wt3);

    const int MB = (N_NODES + 127) / 128;   // 782
    const int ME = (N_EDGES + 127) / 128;   // 157
    const int GE = (N_EDGES / 16) * 8;      // 10000: edge slices x groups
    const int GN = (N_NODES / 32) * 8;      // 25000: node slices x groups
    const int GF = (N_NODES / 32) * 4;      // 12500: node128f slices x groups

    // ---- layer 1: gemm-first (keeps gather rows at 512 B)
    gemm_bf16<<<dim3(MB, 2), 256, 0, stream>>>(xb, Wt1, xw, N_NODES, 320, 256);
    edge_agg_sl<<<GE, 256, 0, stream>>>(xw, offE, endE, csrE, Binv, eb);
    node_agg_sl<<<GN, 256, 0, stream>>>(eb, offN, endN, csrN, Dinv, b1, hb);

    // ---- layer 2: aggregate-first (gemm on 20000 rows)
    edge_agg_sl<<<GE, 256, 0, stream>>>(hb, offE, endE, csrE, Binv, eagg);
    gemm_bf16<<<dim3(ME, 2), 256, 0, stream>>>(eagg, Wt2, eb, N_EDGES, 256, 256);
    node_agg_sl<<<GN, 256, 0, stream>>>(eb, offN, endN, csrN, Dinv, b2, hb);

    // ---- layer 3: aggregate-first, fp32 node output
    edge_agg_sl<<<GE, 256, 0, stream>>>(hb, offE, endE, csrE, Binv, eagg);
    gemm_bf16<<<dim3(ME, 1), 256, 0, stream>>>(eagg, Wt3, eb, N_EDGES, 256, 128);
    node_agg128f_sl<<<GF, 256, 0, stream>>>(eb, offN, endN, csrN, Dinv, b3, h3);

    // ---- attention pooling (fp32)
    logits_kernel<<<400, 256, 0, stream>>>(h3, aW, aB, logits, pmax, N_NODES);
    weighted_sum<<<512, 128, 0, stream>>>(h3, logits, pmax, gacc, gsum, N_NODES);
    finalize<<<1, 128, 0, stream>>>(gacc, gsum, out);
}

// Round 6
// 967.608 us; speedup vs baseline: 1.8286x; 1.8286x over previous
//
#include <hip/hip_runtime.h>
#include <hip/hip_bf16.h>
#include <string.h>

#define N_NODES 100000
#define N_EDGES 20000
#define NNZ     1600000

// CSR-build params: fixed-capacity buckets (mean+>10 sigma), no global scan
#define CHUNK   8192
#define NBE     157            // edge buckets (128 keys each), kshift=17
#define NBN     391            // node buckets (256 keys each), kshift=15
#define CAP_E   11264          // mean 10191, sigma ~101
#define CAP_N   4864           // mean 4092,  sigma ~64
#define NBLK_BIN ((NNZ + CHUNK - 1) / CHUNK)   // 196

// ------------------------------------------------------------ bf16 helpers

__device__ __forceinline__ unsigned short f2bf(float f) {
    unsigned int u = __float_as_uint(f);
    unsigned int r = (u + 0x7fffu + ((u >> 16) & 1u)) >> 16;   // RNE
    return (unsigned short)r;
}
__device__ __forceinline__ float bflo(unsigned int v) { return __uint_as_float(v << 16); }
__device__ __forceinline__ float bfhi(unsigned int v) { return __uint_as_float(v & 0xffff0000u); }
__device__ __forceinline__ unsigned int packbf(float lo, float hi) {
    return ((unsigned int)f2bf(hi) << 16) | (unsigned int)f2bf(lo);
}

__device__ __forceinline__ void async_copy16(const void* g, void* l) {
    __builtin_amdgcn_global_load_lds((const __attribute__((address_space(1))) void*)g,
                                     (__attribute__((address_space(3))) void*)l, 16, 0, 0);
}

typedef __attribute__((ext_vector_type(8))) short bf16x8;
typedef __attribute__((ext_vector_type(4))) float f32x4;

// ---------------------------------------------------- CSR build (capacity buckets)

// one pass over both index arrays: LDS-histogram, reserve global runs,
// scatter packed (key|val) into bucket-strided staging for BOTH directions
__global__ __launch_bounds__(256)
void bin_both(const int* __restrict__ node_idx, const int* __restrict__ edge_idx,
              int* __restrict__ curE, int* __restrict__ curN,
              unsigned int* __restrict__ stagedE, unsigned int* __restrict__ stagedN) {
    __shared__ int hE[NBE], gE[NBE], hN[NBN], gN[NBN];
    int t = threadIdx.x;
    for (int i = t; i < NBE; i += 256) hE[i] = 0;
    for (int i = t; i < NBN; i += 256) hN[i] = 0;
    __syncthreads();
    long base = (long)blockIdx.x * CHUNK;
    for (int k = 0; k < CHUNK / 256; k++) {
        long i = base + t + k * 256;
        if (i < NNZ) {
            atomicAdd(&hE[edge_idx[i] >> 7], 1);
            atomicAdd(&hN[node_idx[i] >> 8], 1);
        }
    }
    __syncthreads();
    for (int i = t; i < NBE; i += 256) gE[i] = hE[i] ? atomicAdd(&curE[i], hE[i]) : 0;
    for (int i = t; i < NBN; i += 256) gN[i] = hN[i] ? atomicAdd(&curN[i], hN[i]) : 0;
    __syncthreads();
    for (int i = t; i < NBE; i += 256) hE[i] = 0;
    for (int i = t; i < NBN; i += 256) hN[i] = 0;
    __syncthreads();
    for (int k = 0; k < CHUNK / 256; k++) {
        long i = base + t + k * 256;
        if (i < NNZ) {
            int e = edge_idx[i], n = node_idx[i];
            int be = e >> 7, bn = n >> 8;
            int pe = gE[be] + atomicAdd(&hE[be], 1);
            if (pe < CAP_E) stagedE[(size_t)be * CAP_E + pe] = ((unsigned)e << 17) | (unsigned)n;
            int pn = gN[bn] + atomicAdd(&hN[bn], 1);
            if (pn < CAP_N) stagedN[(size_t)bn * CAP_N + pn] = ((unsigned)n << 15) | (unsigned)e;
        }
    }
}

// per bucket: per-key count -> local scan -> off/end/inv -> scatter to csr
__global__ __launch_bounds__(256)
void build_csr2(const unsigned int* __restrict__ staged, const int* __restrict__ cnts,
                int cap, int kshift, int bshift, int nkey,
                int* __restrict__ off, int* __restrict__ endv,
                float* __restrict__ inv, int* __restrict__ csr) {
    __shared__ int cnt[256];
    __shared__ int cur[256];
    int b = blockIdx.x, t = threadIdx.x;
    int kpb = 1 << bshift;
    int key0 = b << bshift;
    unsigned int vmask = (1u << kshift) - 1u;
    int s = b * cap;
    int n = min(cnts[b], cap);
    if (t < kpb) cnt[t] = 0;
    __syncthreads();
    for (int j = t; j < n; j += 256)
        atomicAdd(&cnt[(int)(staged[s + j] >> kshift) - key0], 1);
    __syncthreads();
    int v = (t < kpb) ? cnt[t] : 0;
    cur[t] = v; __syncthreads();
    for (int st = 1; st < 256; st <<= 1) {
        int x = (t >= st) ? cur[t - st] : 0;
        __syncthreads();
        cur[t] += x;
        __syncthreads();
    }
    int excl = cur[t] - v;
    __syncthreads();
    if (t < kpb) {
        int key = key0 + t;
        if (key < nkey) {
            off[key] = s + excl;
            endv[key] = s + excl + v;
            inv[key] = (v > 0) ? 1.0f / (float)v : 0.0f;
        }
        cur[t] = excl;
    }
    __syncthreads();
    for (int j = t; j < n; j += 256) {
        unsigned int pk = staged[s + j];
        int k = (int)(pk >> kshift) - key0;
        int pos = s + atomicAdd(&cur[k], 1);
        csr[pos] = (int)(pk & vmask);
    }
}

// ------------------------------------------------------------ prep kernels

// vectorized: 40 threads/row x 8 cols, float4 x2 in, packed-bf16 uint4 out
__global__ __launch_bounds__(256)
void convert_pad_x_v(const float* __restrict__ x, unsigned short* __restrict__ xb) {
    int t = threadIdx.x;
    if (t >= 240) return;
    int c = t % 40;
    int r = blockIdx.x * 6 + t / 40;
    if (r >= N_NODES) return;
    const float* xr = x + (size_t)r * 300 + c * 8;
    uint4 ov;
    if (c < 37) {
        float4 a = ((const float4*)xr)[0];
        float4 b = ((const float4*)xr)[1];
        ov.x = packbf(a.x, a.y); ov.y = packbf(a.z, a.w);
        ov.z = packbf(b.x, b.y); ov.w = packbf(b.z, b.w);
    } else if (c == 37) {                    // cols 296-299 valid, 300-303 pad
        float4 a = ((const float4*)xr)[0];
        ov.x = packbf(a.x, a.y); ov.y = packbf(a.z, a.w);
        ov.z = 0u; ov.w = 0u;
    } else {                                 // cols 304-319 pad
        ov.x = ov.y = ov.z = ov.w = 0u;
    }
    *(uint4*)(xb + (size_t)r * 320 + c * 8) = ov;
}

// all three weight transposes in one launch (grid 640)
__global__ void transpose_all(const float* __restrict__ W1, const float* __restrict__ W2,
                              const float* __restrict__ W3,
                              unsigned short* __restrict__ Wt1, unsigned short* __restrict__ Wt2,
                              unsigned short* __restrict__ Wt3) {
    int b = blockIdx.x;
    int t = threadIdx.x;
    if (b < 256) {
        for (int k = t; k < 320; k += 256)
            Wt1[(size_t)b * 320 + k] = (k < 300) ? f2bf(W1[(size_t)k * 256 + b]) : (unsigned short)0;
    } else if (b < 512) {
        int n = b - 256;
        Wt2[(size_t)n * 256 + t] = f2bf(W2[(size_t)t * 256 + n]);
    } else {
        int n = b - 512;
        Wt3[(size_t)n * 256 + t] = f2bf(W3[(size_t)t * 128 + n]);
    }
}

// ------------------------------------------------------------ bf16 MFMA GEMM

__global__ __launch_bounds__(256)
void gemm_bf16(const unsigned short* __restrict__ A,
               const unsigned short* __restrict__ Bt,
               unsigned short* __restrict__ C,
               int M, int Kp, int N) {
    __shared__ unsigned short As[128 * 32];
    __shared__ unsigned short Bs[128 * 32];
    int tid = threadIdx.x;
    int lane = tid & 63;
    int w = tid >> 6;
    int row0 = blockIdx.x * 128;
    int col0 = blockIdx.y * 128;
    int wm = w & 1, wn = w >> 1;

    f32x4 acc[4][4];
    #pragma unroll
    for (int i = 0; i < 4; i++)
        #pragma unroll
        for (int j = 0; j < 4; j++) acc[i][j] = (f32x4){0.f, 0.f, 0.f, 0.f};

    int sr = lane >> 2;
    int sc = lane & 3;

    for (int k0 = 0; k0 < Kp; k0 += 32) {
        #pragma unroll
        for (int c = 0; c < 2; c++) {
            int r = w * 32 + c * 16 + sr;
            int gr = row0 + r; if (gr >= M) gr = M - 1;
            const unsigned short* g = A + (size_t)gr * Kp + k0 + sc * 8;
            async_copy16(g, (void*)(As + (w * 32 + c * 16) * 32));
        }
        #pragma unroll
        for (int c = 0; c < 2; c++) {
            int r = w * 32 + c * 16 + sr;
            const unsigned short* g = Bt + (size_t)(col0 + r) * Kp + k0 + sc * 8;
            async_copy16(g, (void*)(Bs + (w * 32 + c * 16) * 32));
        }
        __syncthreads();

        bf16x8 a[4], b[4];
        #pragma unroll
        for (int i = 0; i < 4; i++)
            a[i] = *(const bf16x8*)(As + (wm * 64 + i * 16 + (lane & 15)) * 32 + (lane >> 4) * 8);
        #pragma unroll
        for (int j = 0; j < 4; j++)
            b[j] = *(const bf16x8*)(Bs + (wn * 64 + j * 16 + (lane & 15)) * 32 + (lane >> 4) * 8);
        #pragma unroll
        for (int i = 0; i < 4; i++)
            #pragma unroll
            for (int j = 0; j < 4; j++)
                acc[i][j] = __builtin_amdgcn_mfma_f32_16x16x32_bf16(a[i], b[j], acc[i][j], 0, 0, 0);
        __syncthreads();
    }

    int crow = (lane >> 4) * 4;
    int ccol = lane & 15;
    #pragma unroll
    for (int i = 0; i < 4; i++)
        #pragma unroll
        for (int r = 0; r < 4; r++) {
            int gr = row0 + wm * 64 + i * 16 + crow + r;
            if (gr < M) {
                #pragma unroll
                for (int j = 0; j < 4; j++) {
                    int gc = col0 + wn * 64 + j * 16 + ccol;
                    C[(size_t)gr * N + gc] = f2bf(acc[i][j][r]);
                }
            }
        }
}

// ------------------------------------------------------- segment aggregation
// wave-per-segment; 512 B rows loaded as 2 rows/wave (uint4 x 32 lanes each,
// lane halves take alternate members); combine halves via shfl at the end.
// Round 0-5 diagnosis: dur tracks demand bytes (NNZ x row_bytes) through the
// miss path (~7.2 TB/s demand); MLP/schedule changes are null; NT hurts
// (L1 hits matter); feature-slicing for L2 residency loses to per-segment
// overhead. Structural byte reduction is the only lever -> layer 3 runs its
// GEMM first so the edge gather sees 256-B rows (edge_agg128 below).

#define ACC8(v)  { a[0] += bflo((v).x); a[1] += bfhi((v).x); \
                   a[2] += bflo((v).y); a[3] += bfhi((v).y); \
                   a[4] += bflo((v).z); a[5] += bfhi((v).z); \
                   a[6] += bflo((v).w); a[7] += bfhi((v).w); }

__global__ __launch_bounds__(256)
void edge_agg256(const unsigned short* __restrict__ X, const int* __restrict__ off,
                 const int* __restrict__ endv, const int* __restrict__ csr,
                 const float* __restrict__ inv, unsigned short* __restrict__ E) {
    int wv = threadIdx.x >> 6, lane = threadIdx.x & 63;
    int seg = blockIdx.x * 4 + wv;
    if (seg >= N_EDGES) return;
    int s = off[seg], t = endv[seg];
    int half = lane >> 5, l32 = lane & 31;
    const char* Xc = (const char*)X;        // row stride = 512 B
    unsigned lo = (unsigned)l32 << 4;
    float a[8] = {0.f, 0.f, 0.f, 0.f, 0.f, 0.f, 0.f, 0.f};
    int j = s;
    for (; j + 12 <= t; j += 12) {          // 6 pairs, 12 rows in flight
        unsigned o[6];
        #pragma unroll
        for (int q = 0; q < 6; q++) o[q] = ((unsigned)csr[j + 2 * q + half] << 9) + lo;
        uint4 v[6];
        #pragma unroll
        for (int q = 0; q < 6; q++) v[q] = *(const uint4*)(Xc + o[q]);
        __builtin_amdgcn_sched_barrier(0);
        #pragma unroll
        for (int q = 0; q < 6; q++) ACC8(v[q]);
    }
    for (; j + 1 < t; j += 2) {
        uint4 v = *(const uint4*)(Xc + (((unsigned)csr[j + half] << 9) + lo));
        ACC8(v);
    }
    if (j < t && half == 0) {
        uint4 v = *(const uint4*)(Xc + (((unsigned)csr[j] << 9) + lo));
        ACC8(v);
    }
    #pragma unroll
    for (int k = 0; k < 8; k++) a[k] += __shfl_down(a[k], 32);
    if (half == 0) {
        float bi = inv[seg];
        uint4 o;
        o.x = packbf(a[0] * bi, a[1] * bi); o.y = packbf(a[2] * bi, a[3] * bi);
        o.z = packbf(a[4] * bi, a[5] * bi); o.w = packbf(a[6] * bi, a[7] * bi);
        ((uint4*)E)[(size_t)seg * 32 + l32] = o;
    }
}

// layer-3 edge aggregation over 256-B rows (post-GEMM): 4 rows/instr
// (uint4 x 16 lanes each), 16 rows in flight; bf16 out
__global__ __launch_bounds__(256)
void edge_agg128(const unsigned short* __restrict__ X, const int* __restrict__ off,
                 const int* __restrict__ endv, const int* __restrict__ csr,
                 const float* __restrict__ inv, unsigned short* __restrict__ E) {
    int wv = threadIdx.x >> 6, lane = threadIdx.x & 63;
    int seg = blockIdx.x * 4 + wv;
    if (seg >= N_EDGES) return;
    int s = off[seg], t = endv[seg];
    int quad = lane >> 4, l16 = lane & 15;
    const char* Xc = (const char*)X;        // row stride = 256 B
    unsigned lo = (unsigned)l16 << 4;
    float a[8] = {0.f, 0.f, 0.f, 0.f, 0.f, 0.f, 0.f, 0.f};
    int j = s;
    for (; j + 16 <= t; j += 16) {          // 4 quads, 16 rows in flight
        unsigned o[4];
        #pragma unroll
        for (int q = 0; q < 4; q++) o[q] = ((unsigned)csr[j + 4 * q + quad] << 8) + lo;
        uint4 v[4];
        #pragma unroll
        for (int q = 0; q < 4; q++) v[q] = *(const uint4*)(Xc + o[q]);
        __builtin_amdgcn_sched_barrier(0);
        #pragma unroll
        for (int q = 0; q < 4; q++) ACC8(v[q]);
    }
    for (; j + 4 <= t; j += 4) {
        uint4 v = *(const uint4*)(Xc + (((unsigned)csr[j + quad] << 8) + lo));
        ACC8(v);
    }
    if (j < t && j + quad < t) {
        uint4 v = *(const uint4*)(Xc + (((unsigned)csr[j + quad] << 8) + lo));
        ACC8(v);
    }
    #pragma unroll
    for (int k = 0; k < 8; k++) {
        a[k] += __shfl_down(a[k], 32);
        a[k] += __shfl_down(a[k], 16);
    }
    if (lane < 16) {
        float bi = inv[seg];
        uint4 o;
        o.x = packbf(a[0] * bi, a[1] * bi); o.y = packbf(a[2] * bi, a[3] * bi);
        o.z = packbf(a[4] * bi, a[5] * bi); o.w = packbf(a[6] * bi, a[7] * bi);
        *(uint4*)((char*)E + (size_t)seg * 256 + lo) = o;
    }
}

__global__ __launch_bounds__(256)
void node_agg256(const unsigned short* __restrict__ Eb, const int* __restrict__ off,
                 const int* __restrict__ endv, const int* __restrict__ csr,
                 const float* __restrict__ inv, const float* __restrict__ bias,
                 unsigned short* __restrict__ outB) {
    int wv = threadIdx.x >> 6, lane = threadIdx.x & 63;
    int seg = blockIdx.x * 4 + wv;
    if (seg >= N_NODES) return;
    int s = off[seg], t = endv[seg];
    int half = lane >> 5, l32 = lane & 31;
    const char* Ec = (const char*)Eb;       // row stride = 512 B
    unsigned lo = (unsigned)l32 << 4;
    float a[8] = {0.f, 0.f, 0.f, 0.f, 0.f, 0.f, 0.f, 0.f};
    int j = s;
    for (; j + 12 <= t; j += 12) {          // 12 rows in flight
        unsigned o[6];
        #pragma unroll
        for (int q = 0; q < 6; q++) o[q] = ((unsigned)csr[j + 2 * q + half] << 9) + lo;
        uint4 v[6];
        #pragma unroll
        for (int q = 0; q < 6; q++) v[q] = *(const uint4*)(Ec + o[q]);
        __builtin_amdgcn_sched_barrier(0);
        #pragma unroll
        for (int q = 0; q < 6; q++) ACC8(v[q]);
    }
    for (; j + 1 < t; j += 2) {
        uint4 v = *(const uint4*)(Ec + (((unsigned)csr[j + half] << 9) + lo));
        ACC8(v);
    }
    if (j < t && half == 0) {
        uint4 v = *(const uint4*)(Ec + (((unsigned)csr[j] << 9) + lo));
        ACC8(v);
    }
    #pragma unroll
    for (int k = 0; k < 8; k++) a[k] += __shfl_down(a[k], 32);
    if (half == 0) {
        float di = inv[seg];
        float4 b0 = ((const float4*)bias)[l32 * 2];
        float4 b1 = ((const float4*)bias)[l32 * 2 + 1];
        float o0 = a[0] * di + b0.x, o1 = a[1] * di + b0.y;
        float o2 = a[2] * di + b0.z, o3 = a[3] * di + b0.w;
        float o4 = a[4] * di + b1.x, o5 = a[5] * di + b1.y;
        float o6 = a[6] * di + b1.z, o7 = a[7] * di + b1.w;
        o0 = (o0 > 0.f) ? o0 : 0.01f * o0;  o1 = (o1 > 0.f) ? o1 : 0.01f * o1;
        o2 = (o2 > 0.f) ? o2 : 0.01f * o2;  o3 = (o3 > 0.f) ? o3 : 0.01f * o3;
        o4 = (o4 > 0.f) ? o4 : 0.01f * o4;  o5 = (o5 > 0.f) ? o5 : 0.01f * o5;
        o6 = (o6 > 0.f) ? o6 : 0.01f * o6;  o7 = (o7 > 0.f) ? o7 : 0.01f * o7;
        uint4 o;
        o.x = packbf(o0, o1); o.y = packbf(o2, o3);
        o.z = packbf(o4, o5); o.w = packbf(o6, o7);
        ((uint4*)outB)[(size_t)seg * 32 + l32] = o;
    }
}

// F=128 rows (256 B): 4 rows per wave (uint4 x 16 lanes each); fp32 out
__global__ __launch_bounds__(256)
void node_agg128f(const unsigned short* __restrict__ Eb, const int* __restrict__ off,
                  const int* __restrict__ endv, const int* __restrict__ csr,
                  const float* __restrict__ inv, const float* __restrict__ bias,
                  float* __restrict__ outF) {
    int wv = threadIdx.x >> 6, lane = threadIdx.x & 63;
    int seg = blockIdx.x * 4 + wv;
    if (seg >= N_NODES) return;
    int s = off[seg], t = endv[seg];
    int quad = lane >> 4, l16 = lane & 15;
    const char* Ec = (const char*)Eb;       // row stride = 256 B
    unsigned lo = (unsigned)l16 << 4;
    float a[8] = {0.f, 0.f, 0.f, 0.f, 0.f, 0.f, 0.f, 0.f};
    int j = s;
    for (; j + 16 <= t; j += 16) {          // 4 quads, 16 rows in flight
        unsigned o[4];
        #pragma unroll
        for (int q = 0; q < 4; q++) o[q] = ((unsigned)csr[j + 4 * q + quad] << 8) + lo;
        uint4 v[4];
        #pragma unroll
        for (int q = 0; q < 4; q++) v[q] = *(const uint4*)(Ec + o[q]);
        __builtin_amdgcn_sched_barrier(0);
        #pragma unroll
        for (int q = 0; q < 4; q++) ACC8(v[q]);
    }
    for (; j + 4 <= t; j += 4) {
        uint4 v = *(const uint4*)(Ec + (((unsigned)csr[j + quad] << 8) + lo));
        ACC8(v);
    }
    if (j < t && j + quad < t) {
        uint4 v = *(const uint4*)(Ec + (((unsigned)csr[j + quad] << 8) + lo));
        ACC8(v);
    }
    #pragma unroll
    for (int k = 0; k < 8; k++) {
        a[k] += __shfl_down(a[k], 32);
        a[k] += __shfl_down(a[k], 16);
    }
    if (lane < 16) {
        float di = inv[seg];
        float4 b0 = ((const float4*)bias)[l16 * 2];
        float4 b1 = ((const float4*)bias)[l16 * 2 + 1];
        float4 o0 = make_float4(a[0] * di + b0.x, a[1] * di + b0.y,
                                a[2] * di + b0.z, a[3] * di + b0.w);
        float4 o1 = make_float4(a[4] * di + b1.x, a[5] * di + b1.y,
                                a[6] * di + b1.z, a[7] * di + b1.w);
        ((float4*)outF)[(size_t)seg * 32 + l16 * 2]     = o0;
        ((float4*)outF)[(size_t)seg * 32 + l16 * 2 + 1] = o1;
    }
}

// ------------------------------------------------------------- attention pool

__global__ __launch_bounds__(256)
void logits_kernel(const float* __restrict__ H, const float* __restrict__ aW,
                   const float* __restrict__ aB, float* __restrict__ logits,
                   float* __restrict__ pmax, int N) {
    int lane = threadIdx.x & 63;
    int wave = threadIdx.x >> 6;
    int waveGlobal = blockIdx.x * 4 + wave;
    int stride = gridDim.x * 4;
    float2 w2 = ((const float2*)aW)[lane];
    float lmax = -1e30f;
    float ab = aB[0];
    for (int n = waveGlobal; n < N; n += stride) {
        float2 h2 = ((const float2*)(H + (size_t)n * 128))[lane];
        float d = h2.x * w2.x + h2.y * w2.y;
        #pragma unroll
        for (int s = 32; s > 0; s >>= 1) d += __shfl_xor(d, s, 64);
        float lg = d + ab;
        if (lane == 0) logits[n] = lg;
        lmax = fmaxf(lmax, lg);
    }
    __shared__ float wmax[4];
    if (lane == 0) wmax[wave] = lmax;
    __syncthreads();
    if (threadIdx.x == 0) {
        float m = fmaxf(fmaxf(wmax[0], wmax[1]), fmaxf(wmax[2], wmax[3]));
        pmax[blockIdx.x] = m;
    }
}

// global-max reduction folded in (reads pmax[400] per block, ~1 us total)
__global__ __launch_bounds__(128)
void weighted_sum(const float* __restrict__ H, const float* __restrict__ logits,
                  const float* __restrict__ pmax, float* __restrict__ gacc,
                  float* __restrict__ gsum, int N) {
    int f = threadIdx.x;
    __shared__ float smax[2];
    float m = -1e30f;
    for (int i = f; i < 400; i += 128) m = fmaxf(m, pmax[i]);
    #pragma unroll
    for (int s = 32; s > 0; s >>= 1) m = fmaxf(m, __shfl_xor(m, s, 64));
    if ((f & 63) == 0) smax[f >> 6] = m;
    __syncthreads();
    float mx = fmaxf(smax[0], smax[1]);
    float acc = 0.f, ls = 0.f;
    for (int n = blockIdx.x; n < N; n += gridDim.x) {
        float w = __expf(logits[n] - mx);
        acc += w * H[(size_t)n * 128 + f];
        if (f == 0) ls += w;
    }
    atomicAdd(&gacc[f], acc);
    if (f == 0) atomicAdd(gsum, ls);
}

__global__ __launch_bounds__(128)
void finalize(const float* __restrict__ gacc, const float* __restrict__ gsum,
              float* __restrict__ out) {
    int f = threadIdx.x;
    out[f] = gacc[f] / gsum[0];
}

// ---------------------------------------------------------------- launch

extern "C" void kernel_launch(void* const* d_in, const int* in_sizes, int n_in,
                              void* d_out, int out_size, void* d_ws, size_t ws_size,
                              hipStream_t stream) {
    const float* x        = (const float*)d_in[0];
    const int*   node_idx = (const int*)d_in[1];
    const int*   edge_idx = node_idx + NNZ;
    const float* W1 = (const float*)d_in[2];
    const float* b1 = (const float*)d_in[3];
    const float* W2 = (const float*)d_in[4];
    const float* b2 = (const float*)d_in[5];
    const float* W3 = (const float*)d_in[6];
    const float* b3 = (const float*)d_in[7];
    const float* aW = (const float*)d_in[8];
    const float* aB = (const float*)d_in[9];
    float* out = (float*)d_out;

    char* ws = (char*)d_ws;
    size_t off = 0;
    auto take = [&](size_t bytes) -> char* {
        char* r = ws + off;
        off = (off + bytes + 255) & ~(size_t)255;
        return r;
    };

    char* cur_base = take((size_t)(NBE + NBN) * 4);   // zeroed cursors
    int* curE = (int*)cur_base;
    int* curN = curE + NBE;
    int*   offE = (int*)take((size_t)N_EDGES * 4);
    int*   endE = (int*)take((size_t)N_EDGES * 4);
    int*   offN = (int*)take((size_t)N_NODES * 4);
    int*   endN = (int*)take((size_t)N_NODES * 4);
    float* Binv = (float*)take((size_t)N_EDGES * 4);
    float* Dinv = (float*)take((size_t)N_NODES * 4);
    int*   csrE = (int*)take((size_t)NBE * CAP_E * 4);
    int*   csrN = (int*)take((size_t)NBN * CAP_N * 4);

    unsigned short* xb  = (unsigned short*)take((size_t)N_NODES * 320 * 2);  // reused as h3 fp32
    unsigned short* Wt1 = (unsigned short*)take((size_t)256 * 320 * 2);
    unsigned short* Wt2 = (unsigned short*)take((size_t)256 * 256 * 2);
    unsigned short* Wt3 = (unsigned short*)take((size_t)128 * 256 * 2);
    unsigned short* xw   = (unsigned short*)take((size_t)N_NODES * 256 * 2); // gemm1 out; reused layer-3 hw3
    unsigned short* hb   = (unsigned short*)take((size_t)N_NODES * 256 * 2); // node features
    unsigned short* eagg = (unsigned short*)take((size_t)N_EDGES * 256 * 2); // pre-GEMM edge sums (L2)
    unsigned short* eb   = (unsigned short*)take((size_t)N_EDGES * 256 * 2); // edge table
    float* h3 = (float*)xb;

    // staging aliases xw (dead until gemm1; build_csr2 consumes it first)
    unsigned int* stagedE = (unsigned int*)xw;
    unsigned int* stagedN = stagedE + (size_t)NBE * CAP_E;

    float* logits = (float*)take((size_t)N_NODES * 4);
    float* pmax   = (float*)take(400 * 4);
    char* acc_base = take((128 + 1) * 4);
    float* gacc = (float*)acc_base;
    float* gsum = gacc + 128;

    hipMemsetAsync(cur_base, 0, (size_t)(NBE + NBN) * 4, stream);
    hipMemsetAsync(acc_base, 0, (128 + 1) * 4, stream);

    // ---- CSR build: one binning sweep + per-bucket build (both directions)
    bin_both<<<NBLK_BIN, 256, 0, stream>>>(node_idx, edge_idx, curE, curN, stagedE, stagedN);
    build_csr2<<<NBE, 256, 0, stream>>>(stagedE, curE, CAP_E, 17, 7, N_EDGES, offE, endE, Binv, csrE);
    build_csr2<<<NBN, 256, 0, stream>>>(stagedN, curN, CAP_N, 15, 8, N_NODES, offN, endN, Dinv, csrN);

    // ---- prep
    convert_pad_x_v<<<(N_NODES + 5) / 6, 256, 0, stream>>>(x, xb);
    transpose_all<<<640, 256, 0, stream>>>(W1, W2, W3, Wt1, Wt2, Wt3);

    const int MB = (N_NODES + 127) / 128;   // 782
    const int ME = (N_EDGES + 127) / 128;   // 157
    const int EB = N_EDGES / 4;             // 5000
    const int NB = N_NODES / 4;             // 25000

    // ---- layer 1: gemm-first (keeps gather rows at 512 B)
    gemm_bf16<<<dim3(MB, 2), 256, 0, stream>>>(xb, Wt1, xw, N_NODES, 320, 256);
    edge_agg256<<<EB, 256, 0, stream>>>(xw, offE, endE, csrE, Binv, eb);
    node_agg256<<<NB, 256, 0, stream>>>(eb, offN, endN, csrN, Dinv, b1, hb);

    // ---- layer 2: aggregate-first (gemm on 20000 rows)
    edge_agg256<<<EB, 256, 0, stream>>>(hb, offE, endE, csrE, Binv, eagg);
    gemm_bf16<<<dim3(ME, 2), 256, 0, stream>>>(eagg, Wt2, eb, N_EDGES, 256, 256);
    node_agg256<<<NB, 256, 0, stream>>>(eb, offN, endN, csrN, Dinv, b2, hb);

    // ---- layer 3: GEMM-FIRST (linearity: (B^-1 H^T h)W3 == B^-1 H^T (h W3))
    // -> edge gather sees 256-B rows: demand 819->410 MB, table 51->26 MB
    gemm_bf16<<<dim3(MB, 1), 256, 0, stream>>>(hb, Wt3, xw, N_NODES, 256, 128);
    edge_agg128<<<EB, 256, 0, stream>>>(xw, offE, endE, csrE, Binv, eb);
    node_agg128f<<<NB, 256, 0, stream>>>(eb, offN, endN, csrN, Dinv, b3, h3);

    // ---- attention pooling (fp32)
    logits_kernel<<<400, 256, 0, stream>>>(h3, aW, aB, logits, pmax, N_NODES);
    weighted_sum<<<512, 128, 0, stream>>>(h3, logits, pmax, gacc, gsum, N_NODES);
    finalize<<<1, 128, 0, stream>>>(gacc, gsum, out);
}

// Round 7
// 920.556 us; speedup vs baseline: 1.9220x; 1.0511x over previous
//
#include <hip/hip_runtime.h>
#include <hip/hip_bf16.h>
#include <string.h>

#define N_NODES 100000
#define N_EDGES 20000
#define NNZ     1600000

// CSR-build params: fixed-capacity buckets (mean+>10 sigma), no global scan
#define CHUNK   8192
#define NBE     157            // edge buckets (128 keys each), kshift=17
#define NBN     391            // node buckets (256 keys each), kshift=15
#define CAP_E   11264          // mean 10191, sigma ~101
#define CAP_N   4864           // mean 4092,  sigma ~64
#define NBLK_BIN ((NNZ + CHUNK - 1) / CHUNK)   // 196

// ------------------------------------------------------------ bf16 helpers

__device__ __forceinline__ unsigned short f2bf(float f) {
    unsigned int u = __float_as_uint(f);
    unsigned int r = (u + 0x7fffu + ((u >> 16) & 1u)) >> 16;   // RNE
    return (unsigned short)r;
}
__device__ __forceinline__ float bflo(unsigned int v) { return __uint_as_float(v << 16); }
__device__ __forceinline__ float bfhi(unsigned int v) { return __uint_as_float(v & 0xffff0000u); }
__device__ __forceinline__ unsigned int packbf(float lo, float hi) {
    return ((unsigned int)f2bf(hi) << 16) | (unsigned int)f2bf(lo);
}

__device__ __forceinline__ void async_copy16(const void* g, void* l) {
    __builtin_amdgcn_global_load_lds((const __attribute__((address_space(1))) void*)g,
                                     (__attribute__((address_space(3))) void*)l, 16, 0, 0);
}

typedef __attribute__((ext_vector_type(8))) short bf16x8;
typedef __attribute__((ext_vector_type(4))) float f32x4;

// ---------------------------------------------------- CSR build (capacity buckets)

// one pass over both index arrays: LDS-histogram, reserve global runs,
// scatter packed (key|val) into bucket-strided staging for BOTH directions
__global__ __launch_bounds__(256)
void bin_both(const int* __restrict__ node_idx, const int* __restrict__ edge_idx,
              int* __restrict__ curE, int* __restrict__ curN,
              unsigned int* __restrict__ stagedE, unsigned int* __restrict__ stagedN) {
    __shared__ int hE[NBE], gE[NBE], hN[NBN], gN[NBN];
    int t = threadIdx.x;
    for (int i = t; i < NBE; i += 256) hE[i] = 0;
    for (int i = t; i < NBN; i += 256) hN[i] = 0;
    __syncthreads();
    long base = (long)blockIdx.x * CHUNK;
    for (int k = 0; k < CHUNK / 256; k++) {
        long i = base + t + k * 256;
        if (i < NNZ) {
            atomicAdd(&hE[edge_idx[i] >> 7], 1);
            atomicAdd(&hN[node_idx[i] >> 8], 1);
        }
    }
    __syncthreads();
    for (int i = t; i < NBE; i += 256) gE[i] = hE[i] ? atomicAdd(&curE[i], hE[i]) : 0;
    for (int i = t; i < NBN; i += 256) gN[i] = hN[i] ? atomicAdd(&curN[i], hN[i]) : 0;
    __syncthreads();
    for (int i = t; i < NBE; i += 256) hE[i] = 0;
    for (int i = t; i < NBN; i += 256) hN[i] = 0;
    __syncthreads();
    for (int k = 0; k < CHUNK / 256; k++) {
        long i = base + t + k * 256;
        if (i < NNZ) {
            int e = edge_idx[i], n = node_idx[i];
            int be = e >> 7, bn = n >> 8;
            int pe = gE[be] + atomicAdd(&hE[be], 1);
            if (pe < CAP_E) stagedE[(size_t)be * CAP_E + pe] = ((unsigned)e << 17) | (unsigned)n;
            int pn = gN[bn] + atomicAdd(&hN[bn], 1);
            if (pn < CAP_N) stagedN[(size_t)bn * CAP_N + pn] = ((unsigned)n << 15) | (unsigned)e;
        }
    }
}

// per bucket: per-key count -> local scan -> off/end/inv -> scatter to csr
__device__ __forceinline__
void build_csr_dev(const unsigned int* __restrict__ staged, const int* __restrict__ cnts,
                   int b, int cap, int kshift, int bshift, int nkey,
                   int* __restrict__ off, int* __restrict__ endv,
                   float* __restrict__ inv, int* __restrict__ csr,
                   int* cnt, int* cur) {
    int t = threadIdx.x;
    int kpb = 1 << bshift;
    int key0 = b << bshift;
    unsigned int vmask = (1u << kshift) - 1u;
    int s = b * cap;
    int n = min(cnts[b], cap);
    if (t < kpb) cnt[t] = 0;
    __syncthreads();
    for (int j = t; j < n; j += 256)
        atomicAdd(&cnt[(int)(staged[s + j] >> kshift) - key0], 1);
    __syncthreads();
    int v = (t < kpb) ? cnt[t] : 0;
    cur[t] = v; __syncthreads();
    for (int st = 1; st < 256; st <<= 1) {
        int x = (t >= st) ? cur[t - st] : 0;
        __syncthreads();
        cur[t] += x;
        __syncthreads();
    }
    int excl = cur[t] - v;
    __syncthreads();
    if (t < kpb) {
        int key = key0 + t;
        if (key < nkey) {
            off[key] = s + excl;
            endv[key] = s + excl + v;
            inv[key] = (v > 0) ? 1.0f / (float)v : 0.0f;
        }
        cur[t] = excl;
    }
    __syncthreads();
    for (int j = t; j < n; j += 256) {
        unsigned int pk = staged[s + j];
        int k = (int)(pk >> kshift) - key0;
        int pos = s + atomicAdd(&cur[k], 1);
        csr[pos] = (int)(pk & vmask);
    }
}

// both directions in one launch (grid NBE+NBN; branch is block-uniform)
__global__ __launch_bounds__(256)
void build_csr_both(const unsigned int* __restrict__ stagedE, const int* __restrict__ cntsE,
                    int* __restrict__ offE, int* __restrict__ endE,
                    float* __restrict__ invE, int* __restrict__ csrE,
                    const unsigned int* __restrict__ stagedN, const int* __restrict__ cntsN,
                    int* __restrict__ offN, int* __restrict__ endN,
                    float* __restrict__ invN, int* __restrict__ csrN) {
    __shared__ int cnt[256];
    __shared__ int cur[256];
    if (blockIdx.x < NBE)
        build_csr_dev(stagedE, cntsE, blockIdx.x, CAP_E, 17, 7, N_EDGES,
                      offE, endE, invE, csrE, cnt, cur);
    else
        build_csr_dev(stagedN, cntsN, blockIdx.x - NBE, CAP_N, 15, 8, N_NODES,
                      offN, endN, invN, csrN, cnt, cur);
}

// ------------------------------------------------------------ prep kernels

// vectorized: 40 threads/row x 8 cols, float4 x2 in, packed-bf16 uint4 out
__global__ __launch_bounds__(256)
void convert_pad_x_v(const float* __restrict__ x, unsigned short* __restrict__ xb) {
    int t = threadIdx.x;
    if (t >= 240) return;
    int c = t % 40;
    int r = blockIdx.x * 6 + t / 40;
    if (r >= N_NODES) return;
    const float* xr = x + (size_t)r * 300 + c * 8;
    uint4 ov;
    if (c < 37) {
        float4 a = ((const float4*)xr)[0];
        float4 b = ((const float4*)xr)[1];
        ov.x = packbf(a.x, a.y); ov.y = packbf(a.z, a.w);
        ov.z = packbf(b.x, b.y); ov.w = packbf(b.z, b.w);
    } else if (c == 37) {                    // cols 296-299 valid, 300-303 pad
        float4 a = ((const float4*)xr)[0];
        ov.x = packbf(a.x, a.y); ov.y = packbf(a.z, a.w);
        ov.z = 0u; ov.w = 0u;
    } else {                                 // cols 304-319 pad
        ov.x = ov.y = ov.z = ov.w = 0u;
    }
    *(uint4*)(xb + (size_t)r * 320 + c * 8) = ov;
}

// all three weight transposes in one launch (grid 640)
__global__ void transpose_all(const float* __restrict__ W1, const float* __restrict__ W2,
                              const float* __restrict__ W3,
                              unsigned short* __restrict__ Wt1, unsigned short* __restrict__ Wt2,
                              unsigned short* __restrict__ Wt3) {
    int b = blockIdx.x;
    int t = threadIdx.x;
    if (b < 256) {
        for (int k = t; k < 320; k += 256)
            Wt1[(size_t)b * 320 + k] = (k < 300) ? f2bf(W1[(size_t)k * 256 + b]) : (unsigned short)0;
    } else if (b < 512) {
        int n = b - 256;
        Wt2[(size_t)n * 256 + t] = f2bf(W2[(size_t)t * 256 + n]);
    } else {
        int n = b - 512;
        Wt3[(size_t)n * 256 + t] = f2bf(W3[(size_t)t * 128 + n]);
    }
}

// ------------------------------------------------------------ bf16 MFMA GEMM

__global__ __launch_bounds__(256)
void gemm_bf16(const unsigned short* __restrict__ A,
               const unsigned short* __restrict__ Bt,
               unsigned short* __restrict__ C,
               int M, int Kp, int N) {
    __shared__ unsigned short As[128 * 32];
    __shared__ unsigned short Bs[128 * 32];
    int tid = threadIdx.x;
    int lane = tid & 63;
    int w = tid >> 6;
    int row0 = blockIdx.x * 128;
    int col0 = blockIdx.y * 128;
    int wm = w & 1, wn = w >> 1;

    f32x4 acc[4][4];
    #pragma unroll
    for (int i = 0; i < 4; i++)
        #pragma unroll
        for (int j = 0; j < 4; j++) acc[i][j] = (f32x4){0.f, 0.f, 0.f, 0.f};

    int sr = lane >> 2;
    int sc = lane & 3;

    for (int k0 = 0; k0 < Kp; k0 += 32) {
        #pragma unroll
        for (int c = 0; c < 2; c++) {
            int r = w * 32 + c * 16 + sr;
            int gr = row0 + r; if (gr >= M) gr = M - 1;
            const unsigned short* g = A + (size_t)gr * Kp + k0 + sc * 8;
            async_copy16(g, (void*)(As + (w * 32 + c * 16) * 32));
        }
        #pragma unroll
        for (int c = 0; c < 2; c++) {
            int r = w * 32 + c * 16 + sr;
            const unsigned short* g = Bt + (size_t)(col0 + r) * Kp + k0 + sc * 8;
            async_copy16(g, (void*)(Bs + (w * 32 + c * 16) * 32));
        }
        __syncthreads();

        bf16x8 a[4], b[4];
        #pragma unroll
        for (int i = 0; i < 4; i++)
            a[i] = *(const bf16x8*)(As + (wm * 64 + i * 16 + (lane & 15)) * 32 + (lane >> 4) * 8);
        #pragma unroll
        for (int j = 0; j < 4; j++)
            b[j] = *(const bf16x8*)(Bs + (wn * 64 + j * 16 + (lane & 15)) * 32 + (lane >> 4) * 8);
        #pragma unroll
        for (int i = 0; i < 4; i++)
            #pragma unroll
            for (int j = 0; j < 4; j++)
                acc[i][j] = __builtin_amdgcn_mfma_f32_16x16x32_bf16(a[i], b[j], acc[i][j], 0, 0, 0);
        __syncthreads();
    }

    int crow = (lane >> 4) * 4;
    int ccol = lane & 15;
    #pragma unroll
    for (int i = 0; i < 4; i++)
        #pragma unroll
        for (int r = 0; r < 4; r++) {
            int gr = row0 + wm * 64 + i * 16 + crow + r;
            if (gr < M) {
                #pragma unroll
                for (int j = 0; j < 4; j++) {
                    int gc = col0 + wn * 64 + j * 16 + ccol;
                    C[(size_t)gr * N + gc] = f2bf(acc[i][j][r]);
                }
            }
        }
}

// ------------------------------------------------------- segment aggregation
// wave-per-segment; 512 B rows loaded as 2 rows/wave (uint4 x 32 lanes each,
// lane halves take alternate members); combine halves via shfl at the end.
// Rounds 0-6 diagnosis: all gather passes run at ~7.1-7.5 TB/s DEMAND rate
// regardless of table size (node table L2-resident vs edge 46% miss) ->
// per-CU demand/request path is the wall. Byte-proportional model confirmed
// (512-B pass 114 us, 256-B pass ~58 us). Only structural byte reduction
// moves these kernels; bf16 is the precision floor.

#define ACC8(v)  { a[0] += bflo((v).x); a[1] += bfhi((v).x); \
                   a[2] += bflo((v).y); a[3] += bfhi((v).y); \
                   a[4] += bflo((v).z); a[5] += bfhi((v).z); \
                   a[6] += bflo((v).w); a[7] += bfhi((v).w); }

__global__ __launch_bounds__(256)
void edge_agg256(const unsigned short* __restrict__ X, const int* __restrict__ off,
                 const int* __restrict__ endv, const int* __restrict__ csr,
                 const float* __restrict__ inv, unsigned short* __restrict__ E) {
    int wv = threadIdx.x >> 6, lane = threadIdx.x & 63;
    int seg = blockIdx.x * 4 + wv;
    if (seg >= N_EDGES) return;
    int s = off[seg], t = endv[seg];
    int half = lane >> 5, l32 = lane & 31;
    const char* Xc = (const char*)X;        // row stride = 512 B
    unsigned lo = (unsigned)l32 << 4;
    float a[8] = {0.f, 0.f, 0.f, 0.f, 0.f, 0.f, 0.f, 0.f};
    int j = s;
    for (; j + 12 <= t; j += 12) {          // 6 pairs, 12 rows in flight
        unsigned o[6];
        #pragma unroll
        for (int q = 0; q < 6; q++) o[q] = ((unsigned)csr[j + 2 * q + half] << 9) + lo;
        uint4 v[6];
        #pragma unroll
        for (int q = 0; q < 6; q++) v[q] = *(const uint4*)(Xc + o[q]);
        __builtin_amdgcn_sched_barrier(0);
        #pragma unroll
        for (int q = 0; q < 6; q++) ACC8(v[q]);
    }
    for (; j + 1 < t; j += 2) {
        uint4 v = *(const uint4*)(Xc + (((unsigned)csr[j + half] << 9) + lo));
        ACC8(v);
    }
    if (j < t && half == 0) {
        uint4 v = *(const uint4*)(Xc + (((unsigned)csr[j] << 9) + lo));
        ACC8(v);
    }
    #pragma unroll
    for (int k = 0; k < 8; k++) a[k] += __shfl_down(a[k], 32);
    if (half == 0) {
        float bi = inv[seg];
        uint4 o;
        o.x = packbf(a[0] * bi, a[1] * bi); o.y = packbf(a[2] * bi, a[3] * bi);
        o.z = packbf(a[4] * bi, a[5] * bi); o.w = packbf(a[6] * bi, a[7] * bi);
        ((uint4*)E)[(size_t)seg * 32 + l32] = o;
    }
}

// layer-3 edge aggregation over 256-B rows (post-GEMM): 4 rows/instr
// (uint4 x 16 lanes each), 16 rows in flight; bf16 out
__global__ __launch_bounds__(256)
void edge_agg128(const unsigned short* __restrict__ X, const int* __restrict__ off,
                 const int* __restrict__ endv, const int* __restrict__ csr,
                 const float* __restrict__ inv, unsigned short* __restrict__ E) {
    int wv = threadIdx.x >> 6, lane = threadIdx.x & 63;
    int seg = blockIdx.x * 4 + wv;
    if (seg >= N_EDGES) return;
    int s = off[seg], t = endv[seg];
    int quad = lane >> 4, l16 = lane & 15;
    const char* Xc = (const char*)X;        // row stride = 256 B
    unsigned lo = (unsigned)l16 << 4;
    float a[8] = {0.f, 0.f, 0.f, 0.f, 0.f, 0.f, 0.f, 0.f};
    int j = s;
    for (; j + 16 <= t; j += 16) {          // 4 quads, 16 rows in flight
        unsigned o[4];
        #pragma unroll
        for (int q = 0; q < 4; q++) o[q] = ((unsigned)csr[j + 4 * q + quad] << 8) + lo;
        uint4 v[4];
        #pragma unroll
        for (int q = 0; q < 4; q++) v[q] = *(const uint4*)(Xc + o[q]);
        __builtin_amdgcn_sched_barrier(0);
        #pragma unroll
        for (int q = 0; q < 4; q++) ACC8(v[q]);
    }
    for (; j + 4 <= t; j += 4) {
        uint4 v = *(const uint4*)(Xc + (((unsigned)csr[j + quad] << 8) + lo));
        ACC8(v);
    }
    if (j < t && j + quad < t) {
        uint4 v = *(const uint4*)(Xc + (((unsigned)csr[j + quad] << 8) + lo));
        ACC8(v);
    }
    #pragma unroll
    for (int k = 0; k < 8; k++) {
        a[k] += __shfl_down(a[k], 32);
        a[k] += __shfl_down(a[k], 16);
    }
    if (lane < 16) {
        float bi = inv[seg];
        uint4 o;
        o.x = packbf(a[0] * bi, a[1] * bi); o.y = packbf(a[2] * bi, a[3] * bi);
        o.z = packbf(a[4] * bi, a[5] * bi); o.w = packbf(a[6] * bi, a[7] * bi);
        *(uint4*)((char*)E + (size_t)seg * 256 + lo) = o;
    }
}

__global__ __launch_bounds__(256)
void node_agg256(const unsigned short* __restrict__ Eb, const int* __restrict__ off,
                 const int* __restrict__ endv, const int* __restrict__ csr,
                 const float* __restrict__ inv, const float* __restrict__ bias,
                 unsigned short* __restrict__ outB) {
    int wv = threadIdx.x >> 6, lane = threadIdx.x & 63;
    int seg = blockIdx.x * 4 + wv;
    if (seg >= N_NODES) return;
    int s = off[seg], t = endv[seg];
    int half = lane >> 5, l32 = lane & 31;
    const char* Ec = (const char*)Eb;       // row stride = 512 B
    unsigned lo = (unsigned)l32 << 4;
    float a[8] = {0.f, 0.f, 0.f, 0.f, 0.f, 0.f, 0.f, 0.f};
    int j = s;
    for (; j + 12 <= t; j += 12) {          // 12 rows in flight
        unsigned o[6];
        #pragma unroll
        for (int q = 0; q < 6; q++) o[q] = ((unsigned)csr[j + 2 * q + half] << 9) + lo;
        uint4 v[6];
        #pragma unroll
        for (int q = 0; q < 6; q++) v[q] = *(const uint4*)(Ec + o[q]);
        __builtin_amdgcn_sched_barrier(0);
        #pragma unroll
        for (int q = 0; q < 6; q++) ACC8(v[q]);
    }
    for (; j + 1 < t; j += 2) {
        uint4 v = *(const uint4*)(Ec + (((unsigned)csr[j + half] << 9) + lo));
        ACC8(v);
    }
    if (j < t && half == 0) {
        uint4 v = *(const uint4*)(Ec + (((unsigned)csr[j] << 9) + lo));
        ACC8(v);
    }
    #pragma unroll
    for (int k = 0; k < 8; k++) a[k] += __shfl_down(a[k], 32);
    if (half == 0) {
        float di = inv[seg];
        float4 b0 = ((const float4*)bias)[l32 * 2];
        float4 b1 = ((const float4*)bias)[l32 * 2 + 1];
        float o0 = a[0] * di + b0.x, o1 = a[1] * di + b0.y;
        float o2 = a[2] * di + b0.z, o3 = a[3] * di + b0.w;
        float o4 = a[4] * di + b1.x, o5 = a[5] * di + b1.y;
        float o6 = a[6] * di + b1.z, o7 = a[7] * di + b1.w;
        o0 = (o0 > 0.f) ? o0 : 0.01f * o0;  o1 = (o1 > 0.f) ? o1 : 0.01f * o1;
        o2 = (o2 > 0.f) ? o2 : 0.01f * o2;  o3 = (o3 > 0.f) ? o3 : 0.01f * o3;
        o4 = (o4 > 0.f) ? o4 : 0.01f * o4;  o5 = (o5 > 0.f) ? o5 : 0.01f * o5;
        o6 = (o6 > 0.f) ? o6 : 0.01f * o6;  o7 = (o7 > 0.f) ? o7 : 0.01f * o7;
        uint4 o;
        o.x = packbf(o0, o1); o.y = packbf(o2, o3);
        o.z = packbf(o4, o5); o.w = packbf(o6, o7);
        ((uint4*)outB)[(size_t)seg * 32 + l32] = o;
    }
}

// F=128 rows (256 B): 4 rows per wave (uint4 x 16 lanes each); fp32 out.
// FUSED attention logits: lanes 0-15 hold the full h3 row -> dot with aW
// in-register + 4-step shfl reduce, writes logits[seg]. Deletes the separate
// logits_kernel and its full 51-MB re-read of H.
__global__ __launch_bounds__(256)
void node_agg128f_lg(const unsigned short* __restrict__ Eb, const int* __restrict__ off,
                     const int* __restrict__ endv, const int* __restrict__ csr,
                     const float* __restrict__ inv, const float* __restrict__ bias,
                     const float* __restrict__ aW, const float* __restrict__ aB,
                     float* __restrict__ outF, float* __restrict__ logits) {
    int wv = threadIdx.x >> 6, lane = threadIdx.x & 63;
    int seg = blockIdx.x * 4 + wv;
    if (seg >= N_NODES) return;
    int s = off[seg], t = endv[seg];
    int quad = lane >> 4, l16 = lane & 15;
    const char* Ec = (const char*)Eb;       // row stride = 256 B
    unsigned lo = (unsigned)l16 << 4;
    float ab = aB[0];
    float a[8] = {0.f, 0.f, 0.f, 0.f, 0.f, 0.f, 0.f, 0.f};
    int j = s;
    for (; j + 16 <= t; j += 16) {          // 4 quads, 16 rows in flight
        unsigned o[4];
        #pragma unroll
        for (int q = 0; q < 4; q++) o[q] = ((unsigned)csr[j + 4 * q + quad] << 8) + lo;
        uint4 v[4];
        #pragma unroll
        for (int q = 0; q < 4; q++) v[q] = *(const uint4*)(Ec + o[q]);
        __builtin_amdgcn_sched_barrier(0);
        #pragma unroll
        for (int q = 0; q < 4; q++) ACC8(v[q]);
    }
    for (; j + 4 <= t; j += 4) {
        uint4 v = *(const uint4*)(Ec + (((unsigned)csr[j + quad] << 8) + lo));
        ACC8(v);
    }
    if (j < t && j + quad < t) {
        uint4 v = *(const uint4*)(Ec + (((unsigned)csr[j + quad] << 8) + lo));
        ACC8(v);
    }
    #pragma unroll
    for (int k = 0; k < 8; k++) {
        a[k] += __shfl_down(a[k], 32);
        a[k] += __shfl_down(a[k], 16);
    }
    if (lane < 16) {
        float di = inv[seg];
        float4 o0 = make_float4(a[0] * di + ((const float4*)bias)[l16 * 2].x,
                                a[1] * di + ((const float4*)bias)[l16 * 2].y,
                                a[2] * di + ((const float4*)bias)[l16 * 2].z,
                                a[3] * di + ((const float4*)bias)[l16 * 2].w);
        float4 o1 = make_float4(a[4] * di + ((const float4*)bias)[l16 * 2 + 1].x,
                                a[5] * di + ((const float4*)bias)[l16 * 2 + 1].y,
                                a[6] * di + ((const float4*)bias)[l16 * 2 + 1].z,
                                a[7] * di + ((const float4*)bias)[l16 * 2 + 1].w);
        ((float4*)outF)[(size_t)seg * 32 + l16 * 2]     = o0;
        ((float4*)outF)[(size_t)seg * 32 + l16 * 2 + 1] = o1;
        // fused logit: dot(row, aW) over lanes 0-15 (all active here)
        float4 w0 = ((const float4*)aW)[l16 * 2];
        float4 w1 = ((const float4*)aW)[l16 * 2 + 1];
        float d = o0.x * w0.x + o0.y * w0.y + o0.z * w0.z + o0.w * w0.w
                + o1.x * w1.x + o1.y * w1.y + o1.z * w1.z + o1.w * w1.w;
        d += __shfl_down(d, 8);
        d += __shfl_down(d, 4);
        d += __shfl_down(d, 2);
        d += __shfl_down(d, 1);
        if (l16 == 0) logits[seg] = d + ab;
    }
}

// ------------------------------------------------------------- attention pool

// partial max over logits (400 KB): grid 100 x 256 -> pmax[100]
__global__ __launch_bounds__(256)
void lmax_part(const float* __restrict__ logits, float* __restrict__ pmax, int N) {
    int t = threadIdx.x;
    float m = -1e30f;
    for (int i = blockIdx.x * 256 + t; i < N; i += gridDim.x * 256)
        m = fmaxf(m, logits[i]);
    #pragma unroll
    for (int s = 32; s > 0; s >>= 1) m = fmaxf(m, __shfl_xor(m, s, 64));
    __shared__ float wm[4];
    if ((t & 63) == 0) wm[t >> 6] = m;
    __syncthreads();
    if (t == 0)
        pmax[blockIdx.x] = fmaxf(fmaxf(wm[0], wm[1]), fmaxf(wm[2], wm[3]));
}

// global-max fold + weighted sum in one pass over H
__global__ __launch_bounds__(128)
void weighted_sum(const float* __restrict__ H, const float* __restrict__ logits,
                  const float* __restrict__ pmax, float* __restrict__ gacc,
                  float* __restrict__ gsum, int N) {
    int f = threadIdx.x;
    __shared__ float smax[2];
    float m = -1e30f;
    for (int i = f; i < 100; i += 128) m = fmaxf(m, pmax[i]);
    #pragma unroll
    for (int s = 32; s > 0; s >>= 1) m = fmaxf(m, __shfl_xor(m, s, 64));
    if ((f & 63) == 0) smax[f >> 6] = m;
    __syncthreads();
    float mx = fmaxf(smax[0], smax[1]);
    float acc = 0.f, ls = 0.f;
    for (int n = blockIdx.x; n < N; n += gridDim.x) {
        float w = __expf(logits[n] - mx);
        acc += w * H[(size_t)n * 128 + f];
        if (f == 0) ls += w;
    }
    atomicAdd(&gacc[f], acc);
    if (f == 0) atomicAdd(gsum, ls);
}

__global__ __launch_bounds__(128)
void finalize(const float* __restrict__ gacc, const float* __restrict__ gsum,
              float* __restrict__ out) {
    int f = threadIdx.x;
    out[f] = gacc[f] / gsum[0];
}

// ---------------------------------------------------------------- launch

extern "C" void kernel_launch(void* const* d_in, const int* in_sizes, int n_in,
                              void* d_out, int out_size, void* d_ws, size_t ws_size,
                              hipStream_t stream) {
    const float* x        = (const float*)d_in[0];
    const int*   node_idx = (const int*)d_in[1];
    const int*   edge_idx = node_idx + NNZ;
    const float* W1 = (const float*)d_in[2];
    const float* b1 = (const float*)d_in[3];
    const float* W2 = (const float*)d_in[4];
    const float* b2 = (const float*)d_in[5];
    const float* W3 = (const float*)d_in[6];
    const float* b3 = (const float*)d_in[7];
    const float* aW = (const float*)d_in[8];
    const float* aB = (const float*)d_in[9];
    float* out = (float*)d_out;

    char* ws = (char*)d_ws;
    size_t off = 0;
    auto take = [&](size_t bytes) -> char* {
        char* r = ws + off;
        off = (off + bytes + 255) & ~(size_t)255;
        return r;
    };

    char* cur_base = take((size_t)(NBE + NBN) * 4);   // zeroed cursors
    int* curE = (int*)cur_base;
    int* curN = curE + NBE;
    int*   offE = (int*)take((size_t)N_EDGES * 4);
    int*   endE = (int*)take((size_t)N_EDGES * 4);
    int*   offN = (int*)take((size_t)N_NODES * 4);
    int*   endN = (int*)take((size_t)N_NODES * 4);
    float* Binv = (float*)take((size_t)N_EDGES * 4);
    float* Dinv = (float*)take((size_t)N_NODES * 4);
    int*   csrE = (int*)take((size_t)NBE * CAP_E * 4);
    int*   csrN = (int*)take((size_t)NBN * CAP_N * 4);

    unsigned short* xb  = (unsigned short*)take((size_t)N_NODES * 320 * 2);  // reused as h3 fp32
    unsigned short* Wt1 = (unsigned short*)take((size_t)256 * 320 * 2);
    unsigned short* Wt2 = (unsigned short*)take((size_t)256 * 256 * 2);
    unsigned short* Wt3 = (unsigned short*)take((size_t)128 * 256 * 2);
    unsigned short* xw   = (unsigned short*)take((size_t)N_NODES * 256 * 2); // gemm1 out; reused layer-3 hw3
    unsigned short* hb   = (unsigned short*)take((size_t)N_NODES * 256 * 2); // node features
    unsigned short* eagg = (unsigned short*)take((size_t)N_EDGES * 256 * 2); // pre-GEMM edge sums (L2)
    unsigned short* eb   = (unsigned short*)take((size_t)N_EDGES * 256 * 2); // edge table
    float* h3 = (float*)xb;

    // staging aliases xw (dead until gemm1; build_csr consumes it first)
    unsigned int* stagedE = (unsigned int*)xw;
    unsigned int* stagedN = stagedE + (size_t)NBE * CAP_E;

    float* logits = (float*)take((size_t)N_NODES * 4);
    float* pmax   = (float*)take(400 * 4);
    char* acc_base = take((128 + 1) * 4);
    float* gacc = (float*)acc_base;
    float* gsum = gacc + 128;

    hipMemsetAsync(cur_base, 0, (size_t)(NBE + NBN) * 4, stream);
    hipMemsetAsync(acc_base, 0, (128 + 1) * 4, stream);

    // ---- CSR build: one binning sweep + one merged per-bucket build
    bin_both<<<NBLK_BIN, 256, 0, stream>>>(node_idx, edge_idx, curE, curN, stagedE, stagedN);
    build_csr_both<<<NBE + NBN, 256, 0, stream>>>(stagedE, curE, offE, endE, Binv, csrE,
                                                  stagedN, curN, offN, endN, Dinv, csrN);

    // ---- prep
    convert_pad_x_v<<<(N_NODES + 5) / 6, 256, 0, stream>>>(x, xb);
    transpose_all<<<640, 256, 0, stream>>>(W1, W2, W3, Wt1, Wt2, Wt3);

    const int MB = (N_NODES + 127) / 128;   // 782
    const int ME = (N_EDGES + 127) / 128;   // 157
    const int EB = N_EDGES / 4;             // 5000
    const int NB = N_NODES / 4;             // 25000

    // ---- layer 1: gemm-first (keeps gather rows at 512 B)
    gemm_bf16<<<dim3(MB, 2), 256, 0, stream>>>(xb, Wt1, xw, N_NODES, 320, 256);
    edge_agg256<<<EB, 256, 0, stream>>>(xw, offE, endE, csrE, Binv, eb);
    node_agg256<<<NB, 256, 0, stream>>>(eb, offN, endN, csrN, Dinv, b1, hb);

    // ---- layer 2: aggregate-first (gemm on 20000 rows)
    edge_agg256<<<EB, 256, 0, stream>>>(hb, offE, endE, csrE, Binv, eagg);
    gemm_bf16<<<dim3(ME, 2), 256, 0, stream>>>(eagg, Wt2, eb, N_EDGES, 256, 256);
    node_agg256<<<NB, 256, 0, stream>>>(eb, offN, endN, csrN, Dinv, b2, hb);

    // ---- layer 3: GEMM-FIRST (linearity: (B^-1 H^T h)W3 == B^-1 H^T (h W3))
    // -> edge gather sees 256-B rows: demand 819->410 MB, table 51->26 MB
    gemm_bf16<<<dim3(MB, 1), 256, 0, stream>>>(hb, Wt3, xw, N_NODES, 256, 128);
    edge_agg128<<<EB, 256, 0, stream>>>(xw, offE, endE, csrE, Binv, eb);
    node_agg128f_lg<<<NB, 256, 0, stream>>>(eb, offN, endN, csrN, Dinv, b3, aW, aB, h3, logits);

    // ---- attention pooling (logits already fused into node_agg128f_lg)
    lmax_part<<<100, 256, 0, stream>>>(logits, pmax, N_NODES);
    weighted_sum<<<512, 128, 0, stream>>>(h3, logits, pmax, gacc, gsum, N_NODES);
    finalize<<<1, 128, 0, stream>>>(gacc, gsum, out);
}